// Round 4
// baseline (8316.836 us; speedup 1.0000x reference)
//
#include <hip/hip_runtime.h>
#include <math.h>

#define BB 32
#define VV 3
#define SS 106
#define TIN 30
#define WID 32
#define MOD 16
#define NL 6
#define NPIX (SS*SS)
#define KX 32
#define WLAYER (WID*WID*VV*VV*MOD*MOD)
#define ROWF (SS*WID)          // 3392 floats per (b,v,x) row of h
#define AESZ 1024              // floats per (b,v,x) slice of A/G
#define TWO_PI_F 6.2831853071795864769f

// ---------------- fc0 (lift) + forward y-DFT ----------------
// grid B*V*S (b,v,xr). h channel-last: h[blk*3392 + y*32 + c]
// A[blk*1024 + c*32 + ky*2 + ri]
__global__ void k_fc0A(const float* __restrict__ xin, const float* __restrict__ gridx,
                       const float* __restrict__ gridy, const float* __restrict__ fw,
                       const float* __restrict__ fb,
                       float* __restrict__ h, float* __restrict__ A) {
    int blk = blockIdx.x;
    int xr = blk % SS; int bv = blk / SS; int v = bv % VV; int b = bv / VV;
    __shared__ float sxr[SS*31];    // x row, [y][30] pad 31 (13.1 KB)
    __shared__ float sE[SS*33];     // lifted row (13.8 KB)
    __shared__ float2 tw2[112];     // e^{2pi i m/106}
    const float* xrow = xin + ((size_t)(b*VV + v)*SS + xr) * (size_t)(SS*TIN);
    for (int i = threadIdx.x; i < SS*TIN; i += 256) sxr[(i/30)*31 + (i%30)] = xrow[i];
    if (threadIdx.x < SS) {
        float ang = TWO_PI_F * (float)threadIdx.x / (float)SS;
        tw2[threadIdx.x] = make_float2(cosf(ang), sinf(ang));
    }
    __syncthreads();
    float gx = gridx[xr];            // uniform -> sgpr
    int y = threadIdx.x & 127;
    int wg = threadIdx.x >> 7;       // wave-uniform
    if (y < SS) {
        float gy = gridy[y];
        float xv[TIN];
        #pragma unroll
        for (int t = 0; t < TIN; t++) xv[t] = sxr[y*31 + t];
        float acc[16];
        #pragma unroll
        for (int wl = 0; wl < 16; wl++) {
            int w = wg*16 + wl;
            acc[wl] = fb[w] + gx * fw[30*WID + w] + gy * fw[31*WID + w];  // scalar loads
        }
        #pragma unroll
        for (int t = 0; t < TIN; t++) {
            float hv = xv[t];
            #pragma unroll
            for (int wl = 0; wl < 16; wl++)
                acc[wl] = fmaf(hv, fw[t*WID + wg*16 + wl], acc[wl]);      // sgpr weight
        }
        #pragma unroll
        for (int wl = 0; wl < 16; wl++) sE[y*33 + wg*16 + wl] = acc[wl];
    }
    __syncthreads();
    float* hbase = h + (size_t)blk * ROWF;
    for (int i = threadIdx.x*4; i < ROWF; i += 1024)
        *(float4*)(hbase + i) = *(const float4*)&sE[i + (i>>5)];
    // forward y-DFT: A[c][ky] = sum_y sE[y][c] * e^{-i 2pi y ky/106}
    {
        int j = threadIdx.x & 31;
        int kyg = threadIdx.x >> 5;   // 0..7
        int ky0 = kyg*2;
        float r0=0.f,i0=0.f,r1=0.f,i1=0.f;
        int m0 = 0, m1 = 0;
        for (int yy = 0; yy < SS; yy++) {
            float hv = sE[yy*33 + j];
            float2 t0 = tw2[m0];
            float2 t1 = tw2[m1];
            r0 += hv*t0.x; i0 -= hv*t0.y;
            r1 += hv*t1.x; i1 -= hv*t1.y;
            m0 += ky0;   if (m0 >= SS) m0 -= SS;
            m1 += ky0+1; if (m1 >= SS) m1 -= SS;
        }
        __syncthreads();
        *(float4*)&sxr[j*32 + kyg*4] = make_float4(r0, i0, r1, i1);
    }
    __syncthreads();
    float* Abase = A + (size_t)blk * AESZ;
    for (int i = threadIdx.x*4; i < AESZ; i += 1024)
        *(float4*)(Abase + i) = *(const float4*)&sxr[i];
}

// ---------------- stage B: forward x-DFT ----------------
// grid 768: blk -> cg(8), v(3), b(32). block 128. hf[b][kx][ky][ip][2]
__global__ void k_B(const float* __restrict__ A, float* __restrict__ hf) {
    int blk = blockIdx.x;
    int cg = blk & 7; int v = (blk >> 3) % 3; int b = blk / 24;
    __shared__ float stx[SS*64];    // [x][k][2] 27.1 KB
    __shared__ float sAx[8*128];    // 8 x-rows of [c4][ky][2], 4 KB
    __shared__ float2 tw[112];
    if (threadIdx.x < SS) {
        float ang = TWO_PI_F * (float)threadIdx.x / (float)SS;
        tw[threadIdx.x] = make_float2(cosf(ang), sinf(ang));
    }
    __syncthreads();
    for (int i = threadIdx.x; i < SS*KX; i += 128) {
        int x = i >> 5, k = i & 31;
        int kxv = (k < 16) ? k : (k + 74);
        int m = (x * kxv) % SS;
        float2 t = tw[m];
        stx[i*2] = t.x; stx[i*2+1] = t.y;
    }
    int kxh = threadIdx.x >> 6;        // 0..1, wave-uniform
    int ky  = (threadIdx.x >> 2) & 15;
    int c   = threadIdx.x & 3;
    float ar[16], ai[16];
    #pragma unroll
    for (int k = 0; k < 16; k++) { ar[k]=0.f; ai[k]=0.f; }
    const float* Abase = A + ((size_t)(b*VV + v)*SS)*AESZ + cg*128;
    for (int xb = 0; xb < SS; xb += 8) {
        int nx = (SS - xb < 8) ? (SS - xb) : 8;
        __syncthreads();
        for (int i = threadIdx.x; i < nx*32; i += 128) {
            int xl = i >> 5, r = i & 31;
            ((float4*)sAx)[xl*32 + r] = *(const float4*)&Abase[(size_t)(xb+xl)*AESZ + r*4];
        }
        __syncthreads();
        for (int xl = 0; xl < nx; xl++) {
            int x = xb + xl;
            float2 a = *(const float2*)&sAx[xl*128 + c*32 + ky*2];
            #pragma unroll
            for (int kxl = 0; kxl < 16; kxl++) {
                int kx2 = kxh*16 + kxl;
                float tc = stx[x*64 + kx2*2], ts = stx[x*64 + kx2*2 + 1];
                ar[kxl] += a.x*tc + a.y*ts;
                ai[kxl] += a.y*tc - a.x*ts;
            }
        }
    }
    int ip = (cg*4 + c)*3 + v;
    #pragma unroll
    for (int kxl = 0; kxl < 16; kxl++) {
        int kx = kxh*16 + kxl;
        size_t idx = ((((size_t)b*KX + kx)*MOD + ky)*96 + ip)*2;
        hf[idx] = ar[kxl]; hf[idx+1] = ai[kxl];
    }
}

// ---------------- stage C: mode mixing ----------------
// grid (kxi=32, jqc=6, bg=2). oft[b][jq][kx][ky][2]
__global__ void k_C(const float* __restrict__ hf,
                    const float* __restrict__ w1r, const float* __restrict__ w1i,
                    const float* __restrict__ w2r, const float* __restrict__ w2i,
                    float* __restrict__ oft) {
    int kxi = blockIdx.x;
    int jqc = blockIdx.y;
    int bg  = blockIdx.z;
    int ky  = threadIdx.x & 15;
    int jql = threadIdx.x >> 4;
    int jq  = jqc*16 + jql;
    int j = jq / 3, q = jq % 3;
    const float* wr; const float* wi; int kxm = kxi & 15;
    if (kxi < 16) { wr = w1r; wi = w1i; }
    else          { wr = w2r; wi = w2i; }
    float accr[16], acci[16];
    #pragma unroll
    for (int t = 0; t < 16; t++) { accr[t]=0.f; acci[t]=0.f; }
    __shared__ float2 shf2[8*16*17];   // [ipl][bl][ky pad17]
    int sbl = threadIdx.x & 15;
    int sky = threadIdx.x >> 4;
    for (int ip0 = 0; ip0 < 96; ip0 += 8) {
        __syncthreads();
        {
            const float* gsrc = hf + ((((size_t)(bg*16+sbl)*KX + kxi)*MOD + sky)*96 + ip0)*2;
            #pragma unroll
            for (int u = 0; u < 4; u++) {
                float4 f = *(const float4*)(gsrc + u*4);
                shf2[((u*2  )*16 + sbl)*17 + sky] = make_float2(f.x, f.y);
                shf2[((u*2+1)*16 + sbl)*17 + sky] = make_float2(f.z, f.w);
            }
        }
        __syncthreads();
        #pragma unroll
        for (int ipl = 0; ipl < 8; ipl++) {
            int ip = ip0 + ipl;
            int iw = ip / 3, p = ip % 3;
            size_t widx = (((((size_t)iw*WID + j)*VV + p)*VV + q)*MOD + kxm)*MOD + ky;
            float wrv = wr[widx];
            float wiv = wi[widx];
            #pragma unroll
            for (int bl = 0; bl < 16; bl++) {
                float2 hv = shf2[(ipl*16 + bl)*17 + ky];
                accr[bl] += hv.x * wrv - hv.y * wiv;
                acci[bl] += hv.x * wiv + hv.y * wrv;
            }
        }
    }
    #pragma unroll
    for (int bl = 0; bl < 16; bl++) {
        int b = bg*16 + bl;
        float2* out = (float2*)(oft + ((((size_t)b*96 + jq)*KX + kxi)*MOD + ky)*2);
        *out = make_float2(accr[bl], acci[bl]);
    }
}

// ---------------- stage D: inverse x-DFT ----------------
// grid 3072 (b*96+jq), block 128, lane = x. Scalar oft reads, register twiddles.
// G[((b*3+v)*106+x)*1024 + j*32 + ky*2]
__global__ void k_D(const float* __restrict__ oft, float* __restrict__ G) {
    int ch = blockIdx.x;
    int b = ch / 96; int jq = ch % 96; int j = jq / 3; int v = jq % 3;
    __shared__ float2 tw2[112];
    if (threadIdx.x < SS) {
        float ang = TWO_PI_F * (float)threadIdx.x / (float)SS;
        tw2[threadIdx.x] = make_float2(cosf(ang), sinf(ang));
    }
    __syncthreads();
    int x = threadIdx.x;
    if (x >= SS) return;
    float tc[KX], ts[KX];
    {
        int m = 0;
        #pragma unroll
        for (int k = 0; k < 16; k++) {
            float2 t = tw2[m]; tc[k] = t.x; ts[k] = t.y;
            m += x; if (m >= SS) m -= SS;
        }
        m = (x * 90) % SS;
        #pragma unroll
        for (int k = 16; k < 32; k++) {
            float2 t = tw2[m]; tc[k] = t.x; ts[k] = t.y;
            m += x; if (m >= SS) m -= SS;
        }
    }
    const float* so = oft + (size_t)ch * (KX*MOD*2);   // uniform -> s_load
    float gr[MOD], gi[MOD];
    #pragma unroll
    for (int ky = 0; ky < MOD; ky++) { gr[ky]=0.f; gi[ky]=0.f; }
    #pragma unroll 4
    for (int k = 0; k < KX; k++) {
        float tcv = tc[k], tsv = ts[k];
        #pragma unroll
        for (int ky = 0; ky < MOD; ky++) {
            float orr = so[(k*MOD + ky)*2];
            float oii = so[(k*MOD + ky)*2 + 1];
            gr[ky] += orr*tcv - oii*tsv;
            gi[ky] += orr*tsv + oii*tcv;
        }
    }
    float* Gb = G + (((size_t)(b*VV + v)*SS + x))*AESZ + j*32;
    #pragma unroll
    for (int u = 0; u < 8; u++)
        *(float4*)(Gb + u*4) = make_float4(gr[u*2], gi[u*2], gr[u*2+1], gi[u*2+1]);
}

// ---------------- stage E: inverse y-DFT + conv + bias (+gelu) + next y-DFT ----------------
// grid B*V*S. Scalar G/cw reads; register twiddles; LDS only for sE hand-off.
__global__ void k_E(float* __restrict__ G, const float* __restrict__ hold,
                    const float* __restrict__ cw, const float* __restrict__ cb,
                    float* __restrict__ hnew, int do_gelu, int writeA) {
    int blk = blockIdx.x;
    __shared__ float sE[SS*33];       // 13.8 KB
    __shared__ float sA[AESZ];        // 4 KB staging for A write
    __shared__ float2 tw2[112];
    if (threadIdx.x < SS) {
        float ang = TWO_PI_F * (float)threadIdx.x / (float)SS;
        tw2[threadIdx.x] = make_float2(cosf(ang), sinf(ang));
    }
    int y = threadIdx.x & 127;
    int jg = threadIdx.x >> 7;         // wave-uniform
    float hreg[32];
    if (y < SS) {
        const float4* hs = (const float4*)(hold + (size_t)blk * ROWF + (size_t)y*32);
        #pragma unroll
        for (int u = 0; u < 8; u++) {
            float4 f = hs[u];
            hreg[u*4]=f.x; hreg[u*4+1]=f.y; hreg[u*4+2]=f.z; hreg[u*4+3]=f.w;
        }
    }
    __syncthreads();
    const float norm = 1.0f / (float)NPIX;
    const float* Gs = G + (size_t)blk * AESZ;   // uniform -> s_load
    if (y < SS) {
        float tc[MOD], ts[MOD];
        int m = y;
        #pragma unroll
        for (int ky = 1; ky < MOD; ky++) {
            float2 t = tw2[m]; tc[ky] = t.x; ts[ky] = t.y;
            m += y; if (m >= SS) m -= SS;
        }
        for (int jl = 0; jl < 16; jl++) {
            int j = jg*16 + jl;
            const float* gp = Gs + j*32;
            float s = gp[0];
            #pragma unroll
            for (int ky = 1; ky < MOD; ky++)
                s += 2.f * (gp[2*ky] * tc[ky] - gp[2*ky+1] * ts[ky]);
            float acc = fmaf(s, norm, cb[j]);
            #pragma unroll
            for (int c = 0; c < WID; c++)
                acc = fmaf(hreg[c], cw[j*WID + c], acc);   // sgpr weight
            if (do_gelu) acc = 0.5f * acc * (1.f + erff(acc * 0.70710678118654752440f));
            sE[y*33 + j] = acc;
        }
    }
    __syncthreads();
    float* hbase = hnew + (size_t)blk * ROWF;
    for (int i = threadIdx.x*4; i < ROWF; i += 1024)
        *(float4*)(hbase + i) = *(const float4*)&sE[i + (i>>5)];
    if (writeA) {
        int j = threadIdx.x & 31;
        int kyg = threadIdx.x >> 5;
        int ky0 = kyg*2;
        float r0=0.f,i0=0.f,r1=0.f,i1=0.f;
        int m0 = 0, m1 = 0;
        for (int yy = 0; yy < SS; yy++) {
            float hv = sE[yy*33 + j];
            float2 t0 = tw2[m0];
            float2 t1 = tw2[m1];
            r0 += hv*t0.x; i0 -= hv*t0.y;
            r1 += hv*t1.x; i1 -= hv*t1.y;
            m0 += ky0;   if (m0 >= SS) m0 -= SS;
            m1 += ky0+1; if (m1 >= SS) m1 -= SS;
        }
        *(float4*)&sA[j*32 + kyg*4] = make_float4(r0, i0, r1, i1);
        __syncthreads();
        float* Abase = G + (size_t)blk * AESZ;
        for (int i = threadIdx.x*4; i < AESZ; i += 1024)
            *(float4*)(Abase + i) = *(const float4*)&sA[i];
    }
}

// ---------------- head: fc1 + gelu + fc2 ----------------
// grid B*V*S, block 256. Scalar weight reads.
__global__ void k_head(const float* __restrict__ h, const float* __restrict__ fc1w,
                       const float* __restrict__ fc1b, const float* __restrict__ fc2w,
                       const float* __restrict__ fc2b, float* __restrict__ out) {
    int blk = blockIdx.x;
    __shared__ float spart[256];
    int y = threadIdx.x & 127;
    int kh = threadIdx.x >> 7;    // wave-uniform
    float part = 0.f;
    if (y < SS) {
        float hr[WID];
        const float4* hs = (const float4*)(h + (size_t)blk * ROWF + (size_t)y*32);
        #pragma unroll
        for (int u = 0; u < 8; u++) {
            float4 f = hs[u];
            hr[u*4]=f.x; hr[u*4+1]=f.y; hr[u*4+2]=f.z; hr[u*4+3]=f.w;
        }
        for (int kl = 0; kl < 64; kl++) {
            int k = kh*64 + kl;
            float s = fc1b[k];
            #pragma unroll
            for (int c = 0; c < WID; c++)
                s = fmaf(hr[c], fc1w[c*128 + k], s);       // sgpr weight
            s = 0.5f * s * (1.f + erff(s * 0.70710678118654752440f));
            part = fmaf(s, fc2w[k], part);
        }
    }
    spart[threadIdx.x] = part;
    __syncthreads();
    if (kh == 0 && y < SS) {
        out[(size_t)blk*SS + y] = spart[y] + spart[y + 128] + fc2b[0];
    }
}

extern "C" void kernel_launch(void* const* d_in, const int* in_sizes, int n_in,
                              void* d_out, int out_size, void* d_ws, size_t ws_size,
                              hipStream_t stream) {
    const float* xin   = (const float*)d_in[0];
    const float* gridx = (const float*)d_in[1];
    const float* gridy = (const float*)d_in[2];
    const float* fc0w  = (const float*)d_in[3];
    const float* fc0b  = (const float*)d_in[4];
    const float* w1r   = (const float*)d_in[5];
    const float* w1i   = (const float*)d_in[6];
    const float* w2r   = (const float*)d_in[7];
    const float* w2i   = (const float*)d_in[8];
    const float* convw = (const float*)d_in[9];
    const float* convb = (const float*)d_in[10];
    const float* fc1w  = (const float*)d_in[11];
    const float* fc1b  = (const float*)d_in[12];
    const float* fc2w  = (const float*)d_in[13];
    const float* fc2b  = (const float*)d_in[14];
    float* out = (float*)d_out;

    float* p = (float*)d_ws;
    float* h0   = p; p += (size_t)BB*VV*SS*ROWF;
    float* h1   = p; p += (size_t)BB*VV*SS*ROWF;
    float* AG   = p; p += (size_t)BB*VV*SS*AESZ;     // A aliased with G
    float* hfb  = p; p += (size_t)BB*KX*MOD*96*2;
    float* oftb = p; p += (size_t)BB*96*KX*MOD*2;

    k_fc0A<<<BB*VV*SS, 256, 0, stream>>>(xin, gridx, gridy, fc0w, fc0b, h0, AG);

    float* hc = h0; float* hn = h1;
    for (int L = 0; L < NL; L++) {
        k_B<<<BB*VV*8, 128, 0, stream>>>(AG, hfb);
        k_C<<<dim3(KX, 6, 2), 256, 0, stream>>>(hfb,
            w1r + (size_t)L*WLAYER, w1i + (size_t)L*WLAYER,
            w2r + (size_t)L*WLAYER, w2i + (size_t)L*WLAYER, oftb);
        k_D<<<BB*96, 128, 0, stream>>>(oftb, AG);
        k_E<<<BB*VV*SS, 256, 0, stream>>>(AG, hc,
            convw + (size_t)L*WID*WID, convb + (size_t)L*WID, hn,
            (L < 3) ? 1 : 0, (L < NL-1) ? 1 : 0);
        float* tmp = hc; hc = hn; hn = tmp;
    }
    k_head<<<BB*VV*SS, 256, 0, stream>>>(hc, fc1w, fc1b, fc2w, fc2b, out);
}